// Round 1
// baseline (25.004 us; speedup 1.0000x reference)
//
#include <hip/hip_runtime.h>

// E8 attention, closed-form softmax over the E8 root codebook.
//
// Math: for each (token, head) with q in R^8, scores s_r = (q . r)/sqrt(8),
// probs = softmax(s), ctx = sum_r p_r * r.
//   Pair roots (+-1 at i,j; 112 roots): with W_k = exp(q_k/sqrt8),
//     alpha_k = W_k + 1/W_k, beta_k = W_k - 1/W_k:
//     sum_r p_r            = 0.5*(Sa^2 - sum alpha^2),  Sa = sum alpha
//     sum_r p_r * r_i      = beta_i * (Sa - alpha_i)
//   Half roots ((+-1/2)^8, even # of minus; 128 roots): with
//     a_k = 2cosh(q_k/(2 sqrt8)), b_k = 2sinh(q_k/(2 sqrt8)):
//     sum p = 0.5*(prod a + prod b)
//     sum p * r_k = 0.25*(b_k * prod_{m!=k} a_m + a_k * prod_{m!=k} b_m)
// (parity projection: sum over even-parity sign patterns
//   = 0.5*[prod(f+ + f-) + prod(f+ - f-)])
// Exact reformulation of the reference; exp never overflows (|s| ~ 1).

static constexpr int HEADS = 16;
static constexpr int BN = 8 * 4096;  // tokens

__global__ __launch_bounds__(256) void e8_attn_kernel(
    const float* __restrict__ x,
    const float* __restrict__ wq,
    const float* __restrict__ bq,
    const float* __restrict__ wo,
    const float* __restrict__ bo,
    float* __restrict__ out)
{
    const int t = blockIdx.x * 256 + threadIdx.x;
    const int token = t >> 4;
    const int h = t & 15;

    // x[token][0..7] (all 16 head-lanes of a token read the same 32B line)
    const float4 x0 = *(const float4*)(x + token * 8);
    const float4 x1 = *(const float4*)(x + token * 8 + 4);
    const float xv[8] = {x0.x, x0.y, x0.z, x0.w, x1.x, x1.y, x1.z, x1.w};

    // q_j = sum_i x_i * wq[i][h*8+j] + bq[h*8+j]
    float q[8];
    {
        const float4 b0 = *(const float4*)(bq + h * 8);
        const float4 b1 = *(const float4*)(bq + h * 8 + 4);
        q[0] = b0.x; q[1] = b0.y; q[2] = b0.z; q[3] = b0.w;
        q[4] = b1.x; q[5] = b1.y; q[6] = b1.z; q[7] = b1.w;
        #pragma unroll
        for (int i = 0; i < 8; ++i) {
            const float4 w0 = *(const float4*)(wq + i * 128 + h * 8);
            const float4 w1 = *(const float4*)(wq + i * 128 + h * 8 + 4);
            q[0] = fmaf(xv[i], w0.x, q[0]);
            q[1] = fmaf(xv[i], w0.y, q[1]);
            q[2] = fmaf(xv[i], w0.z, q[2]);
            q[3] = fmaf(xv[i], w0.w, q[3]);
            q[4] = fmaf(xv[i], w1.x, q[4]);
            q[5] = fmaf(xv[i], w1.y, q[5]);
            q[6] = fmaf(xv[i], w1.z, q[6]);
            q[7] = fmaf(xv[i], w1.w, q[7]);
        }
    }

    const float C1 = 0.17677669529663688f;  // 0.5/sqrt(8)
    float alpha[8], beta[8], a[8], b[8];
    #pragma unroll
    for (int k = 0; k < 8; ++k) {
        const float w  = __expf(C1 * q[k]);          // exp(q/(2 sqrt 8))
        const float iw = __builtin_amdgcn_rcpf(w);
        const float W  = w * w;                      // exp(q/sqrt 8)
        const float iW = iw * iw;
        alpha[k] = W + iW;
        beta[k]  = W - iW;
        a[k] = w + iw;
        b[k] = w - iw;
    }

    float Sa = 0.f, Sa2 = 0.f;
    #pragma unroll
    for (int k = 0; k < 8; ++k) { Sa += alpha[k]; Sa2 = fmaf(alpha[k], alpha[k], Sa2); }
    const float l_pair = 0.5f * (Sa * Sa - Sa2);

    // prefix/suffix products for leave-one-out products of a[] and b[]
    float preA[8], preB[8], sufA[8], sufB[8];
    preA[0] = 1.f; preB[0] = 1.f;
    #pragma unroll
    for (int k = 1; k < 8; ++k) { preA[k] = preA[k-1] * a[k-1]; preB[k] = preB[k-1] * b[k-1]; }
    sufA[7] = 1.f; sufB[7] = 1.f;
    #pragma unroll
    for (int k = 6; k >= 0; --k) { sufA[k] = sufA[k+1] * a[k+1]; sufB[k] = sufB[k+1] * b[k+1]; }
    const float PA = preA[7] * a[7];
    const float PB = preB[7] * b[7];

    const float l  = l_pair + 0.5f * (PA + PB);
    const float rl = __builtin_amdgcn_rcpf(l);

    float ctx[8];
    #pragma unroll
    for (int k = 0; k < 8; ++k) {
        const float Abar = preA[k] * sufA[k];
        const float Bbar = preB[k] * sufB[k];
        ctx[k] = (beta[k] * (Sa - alpha[k]) + 0.25f * (b[k] * Abar + a[k] * Bbar)) * rl;
    }

    // out_j partial for this head: sum_k ctx_k * wo[(h*8+k)*8 + j]
    float po[8] = {0.f,0.f,0.f,0.f,0.f,0.f,0.f,0.f};
    const float* wo_h = wo + h * 64;
    #pragma unroll
    for (int k = 0; k < 8; ++k) {
        const float4 w0 = *(const float4*)(wo_h + k * 8);
        const float4 w1 = *(const float4*)(wo_h + k * 8 + 4);
        po[0] = fmaf(ctx[k], w0.x, po[0]);
        po[1] = fmaf(ctx[k], w0.y, po[1]);
        po[2] = fmaf(ctx[k], w0.z, po[2]);
        po[3] = fmaf(ctx[k], w0.w, po[3]);
        po[4] = fmaf(ctx[k], w1.x, po[4]);
        po[5] = fmaf(ctx[k], w1.y, po[5]);
        po[6] = fmaf(ctx[k], w1.z, po[6]);
        po[7] = fmaf(ctx[k], w1.w, po[7]);
    }

    // reduce over the 16 head-lanes of this token (lanes h=0..15 in-group)
    #pragma unroll
    for (int m = 1; m < 16; m <<= 1) {
        #pragma unroll
        for (int j = 0; j < 8; ++j) po[j] += __shfl_xor(po[j], m, 64);
    }

    if (h == 0) {
        const float4 c0 = *(const float4*)(bo);
        const float4 c1 = *(const float4*)(bo + 4);
        float4 o0, o1;
        o0.x = po[0] + c0.x; o0.y = po[1] + c0.y; o0.z = po[2] + c0.z; o0.w = po[3] + c0.w;
        o1.x = po[4] + c1.x; o1.y = po[5] + c1.y; o1.z = po[6] + c1.z; o1.w = po[7] + c1.w;
        *(float4*)(out + token * 8)     = o0;
        *(float4*)(out + token * 8 + 4) = o1;
    }
}

extern "C" void kernel_launch(void* const* d_in, const int* in_sizes, int n_in,
                              void* d_out, int out_size, void* d_ws, size_t ws_size,
                              hipStream_t stream) {
    const float* x  = (const float*)d_in[0];
    const float* wq = (const float*)d_in[1];
    const float* bq = (const float*)d_in[2];
    // d_in[3..6] = wk, bk, wv, bv: dead code in the reference
    const float* wo = (const float*)d_in[7];
    const float* bo = (const float*)d_in[8];
    float* out = (float*)d_out;

    const int threads = BN * HEADS;          // 524288 = 2048 blocks * 256
    e8_attn_kernel<<<threads / 256, 256, 0, stream>>>(x, wq, bq, wo, bo, out);
}

// Round 2
// 16.423 us; speedup vs baseline: 1.5225x; 1.5225x over previous
//
#include <hip/hip_runtime.h>

// E8 attention, closed-form softmax over the E8 root codebook.
//
// For each (token, head) with q in R^8, s_r = (q.r)/sqrt(8), p = softmax(s),
// ctx = sum_r p_r r. With c = 1/(2 sqrt 8), w_k = exp(c q_k), iw = 1/w:
//   a_k = w + iw (= 2cosh(c q_k)),  b_k = w - iw (= 2sinh(c q_k))
//   alpha_k = a_k^2 - 2 (= 2cosh(2c q_k)),  beta_k = a_k b_k (= 2sinh(2c q_k))
// Pair roots (+-1 at i,j; 112): numer_i = beta_i (Sa - alpha_i),
//   denom = 0.5 (Sa^2 - sum alpha^2),  Sa = sum alpha.
// Half roots ((+-1/2)^8, even parity; 128): parity projection
//   denom = 0.5 (prod a + prod b),
//   numer_k = 0.25 (b_k prod_{m!=k} a_m + a_k prod_{m!=k} b_m).
// Exact reformulation; |scores| ~ 1 so exp cannot overflow in f32.
//
// Layout: 16 lanes per token (one per head), T=2 tokens per thread so the
// wq/wo loads amortize and the two token pipelines interleave for ILP.
// Output projection partials are reduce-scattered over the 16 head lanes
// (component set halves per stage; lane h ends owning component j = h>>1).

static constexpr int HEADS = 16;
static constexpr int BN = 8 * 4096;  // tokens
static constexpr int T = 2;          // tokens per thread

__global__ __launch_bounds__(256) void e8_attn_kernel(
    const float* __restrict__ x,
    const float* __restrict__ wq,
    const float* __restrict__ bq,
    const float* __restrict__ wo,
    const float* __restrict__ bo,
    float* __restrict__ out)
{
    const int t = blockIdx.x * 256 + threadIdx.x;
    const int p = t >> 4;        // token-pair index
    const int h = t & 15;        // head
    const int tok = p * T;

    // ---- x for T tokens ----
    float xv[T][8];
#pragma unroll
    for (int u = 0; u < T; ++u) {
        const float4 x0 = *(const float4*)(x + (tok + u) * 8);
        const float4 x1 = *(const float4*)(x + (tok + u) * 8 + 4);
        xv[u][0] = x0.x; xv[u][1] = x0.y; xv[u][2] = x0.z; xv[u][3] = x0.w;
        xv[u][4] = x1.x; xv[u][5] = x1.y; xv[u][6] = x1.z; xv[u][7] = x1.w;
    }

    // ---- q = x @ wq + bq (per head), wq loads shared across the T tokens ----
    float q[T][8];
    {
        const float4 b0 = *(const float4*)(bq + h * 8);
        const float4 b1 = *(const float4*)(bq + h * 8 + 4);
#pragma unroll
        for (int u = 0; u < T; ++u) {
            q[u][0] = b0.x; q[u][1] = b0.y; q[u][2] = b0.z; q[u][3] = b0.w;
            q[u][4] = b1.x; q[u][5] = b1.y; q[u][6] = b1.z; q[u][7] = b1.w;
        }
#pragma unroll
        for (int i = 0; i < 8; ++i) {
            const float4 w0 = *(const float4*)(wq + i * 128 + h * 8);
            const float4 w1 = *(const float4*)(wq + i * 128 + h * 8 + 4);
#pragma unroll
            for (int u = 0; u < T; ++u) {
                q[u][0] = fmaf(xv[u][i], w0.x, q[u][0]);
                q[u][1] = fmaf(xv[u][i], w0.y, q[u][1]);
                q[u][2] = fmaf(xv[u][i], w0.z, q[u][2]);
                q[u][3] = fmaf(xv[u][i], w0.w, q[u][3]);
                q[u][4] = fmaf(xv[u][i], w1.x, q[u][4]);
                q[u][5] = fmaf(xv[u][i], w1.y, q[u][5]);
                q[u][6] = fmaf(xv[u][i], w1.z, q[u][6]);
                q[u][7] = fmaf(xv[u][i], w1.w, q[u][7]);
            }
        }
    }

    // ---- hyperbolic building blocks: a=2cosh(cq), b=2sinh(cq) ----
    // exp2 form: w = 2^(C2*q), C2 = log2(e)/(2*sqrt(8))
    const float C2 = 0.25506807186927930f;
    float a[T][8], b[T][8];
    float Sa[T], Sa2[T];
#pragma unroll
    for (int u = 0; u < T; ++u) { Sa[u] = 0.f; Sa2[u] = 0.f; }
#pragma unroll
    for (int k = 0; k < 8; ++k) {
#pragma unroll
        for (int u = 0; u < T; ++u) {
            const float w  = __builtin_exp2f(C2 * q[u][k]);
            const float iw = __builtin_amdgcn_rcpf(w);
            const float av = w + iw;
            const float bv = w - iw;
            a[u][k] = av; b[u][k] = bv;
            const float alpha = fmaf(av, av, -2.0f);
            Sa[u] += alpha;
            Sa2[u] = fmaf(alpha, alpha, Sa2[u]);
        }
    }

    // ---- suffix products; denominator; reciprocal ----
    float sufA[T][8], sufB[T][8], rl[T];
#pragma unroll
    for (int u = 0; u < T; ++u) { sufA[u][7] = 1.f; sufB[u][7] = 1.f; }
#pragma unroll
    for (int k = 6; k >= 0; --k) {
#pragma unroll
        for (int u = 0; u < T; ++u) {
            sufA[u][k] = sufA[u][k + 1] * a[u][k + 1];
            sufB[u][k] = sufB[u][k + 1] * b[u][k + 1];
        }
    }
#pragma unroll
    for (int u = 0; u < T; ++u) {
        const float PA = a[u][0] * sufA[u][0];
        const float PB = b[u][0] * sufB[u][0];
        const float l = 0.5f * (Sa[u] * Sa[u] - Sa2[u]) + 0.5f * (PA + PB);
        rl[u] = __builtin_amdgcn_rcpf(l);
    }

    // ---- fused ctx + output projection: po_j += ctx_k * wo[h*64+k*8+j] ----
    float po[T][8];
#pragma unroll
    for (int u = 0; u < T; ++u)
#pragma unroll
        for (int j = 0; j < 8; ++j) po[u][j] = 0.f;

    float preA[T], preB[T];
#pragma unroll
    for (int u = 0; u < T; ++u) { preA[u] = 1.f; preB[u] = 1.f; }

    const float* wo_h = wo + h * 64;
#pragma unroll
    for (int k = 0; k < 8; ++k) {
        const float4 w0 = *(const float4*)(wo_h + k * 8);
        const float4 w1 = *(const float4*)(wo_h + k * 8 + 4);
#pragma unroll
        for (int u = 0; u < T; ++u) {
            const float av = a[u][k], bv = b[u][k];
            const float Abar = preA[u] * sufA[u][k];
            const float Bbar = preB[u] * sufB[u][k];
            const float alpha = fmaf(av, av, -2.0f);
            const float pair = (av * bv) * (Sa[u] - alpha);
            const float half = 0.25f * fmaf(bv, Abar, av * Bbar);
            const float ctx = (pair + half) * rl[u];
            preA[u] *= av; preB[u] *= bv;
            po[u][0] = fmaf(ctx, w0.x, po[u][0]);
            po[u][1] = fmaf(ctx, w0.y, po[u][1]);
            po[u][2] = fmaf(ctx, w0.z, po[u][2]);
            po[u][3] = fmaf(ctx, w0.w, po[u][3]);
            po[u][4] = fmaf(ctx, w1.x, po[u][4]);
            po[u][5] = fmaf(ctx, w1.y, po[u][5]);
            po[u][6] = fmaf(ctx, w1.z, po[u][6]);
            po[u][7] = fmaf(ctx, w1.w, po[u][7]);
        }
    }

    // ---- reduce-scatter over the 16 head lanes ----
    // stage 1 (xor 8): keep components with j2 == h3  -> 4 per lane
    const bool h3 = (h & 8) != 0;
    const bool h2 = (h & 4) != 0;
    const bool h1 = (h & 2) != 0;
    float r4[T][4];
#pragma unroll
    for (int u = 0; u < T; ++u)
#pragma unroll
        for (int m = 0; m < 4; ++m) {
            const float send = h3 ? po[u][m] : po[u][4 + m];
            const float keep = h3 ? po[u][4 + m] : po[u][m];
            r4[u][m] = keep + __shfl_xor(send, 8, 64);
        }
    // stage 2 (xor 4): keep j1 == h2 -> 2 per lane
    float r2[T][2];
#pragma unroll
    for (int u = 0; u < T; ++u)
#pragma unroll
        for (int m = 0; m < 2; ++m) {
            const float send = h2 ? r4[u][m] : r4[u][2 + m];
            const float keep = h2 ? r4[u][2 + m] : r4[u][m];
            r2[u][m] = keep + __shfl_xor(send, 4, 64);
        }
    // stage 3 (xor 2): keep j0 == h1 -> 1 per lane (component j = h>>1)
    float r1[T];
#pragma unroll
    for (int u = 0; u < T; ++u) {
        const float send = h1 ? r2[u][0] : r2[u][1];
        const float keep = h1 ? r2[u][1] : r2[u][0];
        r1[u] = keep + __shfl_xor(send, 2, 64);
    }
    // stage 4 (xor 1): sum the two remaining partials
#pragma unroll
    for (int u = 0; u < T; ++u) r1[u] += __shfl_xor(r1[u], 1, 64);

    // lane h (h even) owns output component j = h>>1 for its T tokens
    const int j = h >> 1;
    const float boj = bo[j];
    if ((h & 1) == 0) {
#pragma unroll
        for (int u = 0; u < T; ++u)
            out[(tok + u) * 8 + j] = r1[u] + boj;
    }
}

extern "C" void kernel_launch(void* const* d_in, const int* in_sizes, int n_in,
                              void* d_out, int out_size, void* d_ws, size_t ws_size,
                              hipStream_t stream) {
    const float* x  = (const float*)d_in[0];
    const float* wq = (const float*)d_in[1];
    const float* bq = (const float*)d_in[2];
    // d_in[3..6] = wk, bk, wv, bv: dead code in the reference
    const float* wo = (const float*)d_in[7];
    const float* bo = (const float*)d_in[8];
    float* out = (float*)d_out;

    const int threads = (BN / T) * HEADS;   // 262144 -> 1024 blocks x 256
    e8_attn_kernel<<<threads / 256, 256, 0, stream>>>(x, wq, bq, wo, bo, out);
}